// Round 1
// baseline (1589.598 us; speedup 1.0000x reference)
//
#include <hip/hip_runtime.h>
#include <hip/hip_bf16.h>
#include <cmath>

// Problem constants
#define BB 2
#define TT 2048
#define CC 1024
#define HH 16
#define DD 64
#define ROWS (BB*TT)          // 4096
#define N1 (3*CC)             // 3072
#define EPS 1e-6f

using short8 = __attribute__((ext_vector_type(8))) short;
using f32x4  = __attribute__((ext_vector_type(4))) float;

// ---------------------------------------------------------------- rope table
// rope[pos*64 + 2*i] = cos(pos*freq_i), +1 = sin. freq_i = 10000^(-i/32)
__global__ void rope_init(float* __restrict__ rope) {
    int idx = blockIdx.x * 256 + threadIdx.x;      // 0 .. T*32-1
    if (idx >= TT * 32) return;
    int t = idx >> 5, i = idx & 31;
    double freq = pow(10000.0, -(double)i / 32.0);
    float ang = (float)t * (float)freq;
    rope[idx * 2 + 0] = cosf(ang);
    rope[idx * 2 + 1] = sinf(ang);
}

// ------------------------------------------- row sum-of-squares + bf16 cast
__global__ void rowsq_cast(const float* __restrict__ X, float* __restrict__ xsq,
                           __hip_bfloat16* __restrict__ Xb) {
    int row = blockIdx.x;
    int t = threadIdx.x;
    const float* xr = X + (size_t)row * CC;
    __hip_bfloat16* br = Xb + (size_t)row * CC;
    float p = 0.f;
#pragma unroll
    for (int i = 0; i < 4; ++i) {
        float v = xr[t + i * 256];
        p += v * v;
        br[t + i * 256] = (__hip_bfloat16)v;
    }
    __shared__ float s[256];
    s[t] = p;
    __syncthreads();
    for (int off = 128; off > 0; off >>= 1) {
        if (t < off) s[t] += s[t + off];
        __syncthreads();
    }
    if (t == 0) xsq[row] = s[0];
}

// --------------------- transpose W (K x N fp32) -> Wt (N x K bf16) + col sq
__global__ void transpose_colsq(const float* __restrict__ W,
                                __hip_bfloat16* __restrict__ Wt,
                                float* __restrict__ wsq, int K, int N) {
    __shared__ unsigned short tile[64][65];
    int n0 = blockIdx.x * 64, k0 = blockIdx.y * 64;
    int c = threadIdx.x & 63, rg = threadIdx.x >> 6;
    float part = 0.f;
#pragma unroll
    for (int rr = 0; rr < 16; ++rr) {
        int r = rg + rr * 4;
        float f = W[(size_t)(k0 + r) * N + n0 + c];
        __hip_bfloat16 h = (__hip_bfloat16)f;
        tile[r][c] = *(unsigned short*)&h;
        part += f * f;
    }
    atomicAdd(&wsq[n0 + c], part);
    __syncthreads();
#pragma unroll
    for (int rr = 0; rr < 16; ++rr) {
        int r = rg + rr * 4;
        unsigned short u = tile[c][r];
        Wt[(size_t)(n0 + r) * K + k0 + c] = *(__hip_bfloat16*)&u;
    }
}

// ----------------------------------------- MFMA bf16 GEMM with yat epilogue
// C[M][N] (fp32) = yat( A[M][K](bf16) * Bt[N][K](bf16)^T )
__global__ __launch_bounds__(256) void yat_gemm(
    const __hip_bfloat16* __restrict__ A,
    const __hip_bfloat16* __restrict__ Bt,
    const float* __restrict__ xsq, const float* __restrict__ wsq,
    const float* __restrict__ bias, float* __restrict__ C,
    int M, int N, int K, float scale) {
    __shared__ __align__(16) unsigned short As[64 * 32];
    __shared__ __align__(16) unsigned short Bs[64 * 32];
    int tid = threadIdx.x;
    int wave = tid >> 6, lane = tid & 63;
    int quad = lane >> 4, l16 = lane & 15;
    int m0 = blockIdx.y * 64, n0 = blockIdx.x * 64;

    f32x4 acc[4] = {};
    int ar = tid >> 2;              // staging row 0..63
    int ak = (tid & 3) << 3;        // staging k offset 0/8/16/24
    const __hip_bfloat16* Ap = A + (size_t)(m0 + ar) * K + ak;
    const __hip_bfloat16* Bp = Bt + (size_t)(n0 + ar) * K + ak;

    for (int k0 = 0; k0 < K; k0 += 32) {
        uint4 av = *(const uint4*)(Ap + k0);
        uint4 bv = *(const uint4*)(Bp + k0);
        __syncthreads();
        *(uint4*)(As + tid * 8) = av;   // LDS row-major 64x32, offset = ar*32+ak
        *(uint4*)(Bs + tid * 8) = bv;
        __syncthreads();
        short8 afrag = *(const short8*)(As + (wave * 16 + l16) * 32 + quad * 8);
#pragma unroll
        for (int nb = 0; nb < 4; ++nb) {
            short8 bfrag = *(const short8*)(Bs + (nb * 16 + l16) * 32 + quad * 8);
            acc[nb] = __builtin_amdgcn_mfma_f32_16x16x32_bf16(afrag, bfrag, acc[nb], 0, 0, 0);
        }
    }
    // epilogue: C[m = quad*4+reg][n = l16] per 16x16 tile
    int mbase = m0 + wave * 16 + quad * 4;
#pragma unroll
    for (int nb = 0; nb < 4; ++nb) {
        int col = n0 + nb * 16 + l16;
        float wq = wsq[col];
        float bs = bias[col];
#pragma unroll
        for (int r = 0; r < 4; ++r) {
            int row = mbase + r;
            float dot = acc[nb][r];
            float dist = xsq[row] + wq - 2.f * dot + EPS;
            float y = dot * dot / dist * scale + bs;
            C[(size_t)row * N + col] = y;
        }
    }
}

// ------------------------------------------------ fp32 flash attention
// grid (32 qblk, 16 h, 2 b), block 256. Reads fp32 qkv, writes bf16 attn_out
// (row-major [B*T][C]) and accumulates fp32 o_sq (sum over C of out^2).
__global__ __launch_bounds__(256) void attn_kernel(
    const float* __restrict__ qkv, const float* __restrict__ rope,
    __hip_bfloat16* __restrict__ out, float* __restrict__ osq) {
    int qblk = 31 - blockIdx.x;     // heavy blocks first
    int h = blockIdx.y, b = blockIdx.z;
    int q0 = qblk * 64;
    int tid = threadIdx.x;
    int r = tid >> 2;       // q row 0..63
    int g = tid & 3;        // group 0..3

    __shared__ float Qs[64][65];
    __shared__ float Ks[32][65];
    __shared__ float Vs[32][65];
    __shared__ float Ss[64][33];
    __shared__ float red[64][8];

    // load Q tile with rope, pre-scaled by 1/sqrt(D)=0.125
    {
        const float* qrow = qkv + (size_t)(b * TT + q0 + r) * N1 + h * DD;
        const float* rp = rope + (size_t)(q0 + r) * 64;
#pragma unroll
        for (int u = 0; u < 8; ++u) {
            int d0 = g * 16 + u * 2;
            int i = d0 >> 1;
            float cs = rp[2 * i], sn = rp[2 * i + 1];
            float t0 = qrow[d0], t1 = qrow[d0 + 1];
            Qs[r][d0]     = (t0 * cs - t1 * sn) * 0.125f;
            Qs[r][d0 + 1] = (t1 * cs + t0 * sn) * 0.125f;
        }
    }
    float m_old = -INFINITY, l = 0.f;
    float O[16];
#pragma unroll
    for (int u = 0; u < 16; ++u) O[u] = 0.f;

    int ntiles = 2 * qblk + 2;
    for (int kt = 0; kt < ntiles; ++kt) {
        int k0 = kt * 32;
        __syncthreads();     // protect Ks/Vs (and Ss) from previous iteration
        {   // load K (rope) and V tiles: 32 rows x 64 d
            int j = tid >> 3, dd = (tid & 7) * 8;
            int kp = k0 + j;
            const float* krow = qkv + (size_t)(b * TT + kp) * N1 + CC + h * DD;
            const float* vrow = qkv + (size_t)(b * TT + kp) * N1 + 2 * CC + h * DD;
            const float* rpk = rope + (size_t)kp * 64;
#pragma unroll
            for (int u = 0; u < 4; ++u) {
                int d0 = dd + u * 2;
                int i = d0 >> 1;
                float cs = rpk[2 * i], sn = rpk[2 * i + 1];
                float t0 = krow[d0], t1 = krow[d0 + 1];
                Ks[j][d0]     = t0 * cs - t1 * sn;
                Ks[j][d0 + 1] = t1 * cs + t0 * sn;
                Vs[j][d0]     = vrow[d0];
                Vs[j][d0 + 1] = vrow[d0 + 1];
            }
        }
        __syncthreads();
        // S phase: thread computes S[r][g*8 .. g*8+7]
        float dots[8];
#pragma unroll
        for (int jj = 0; jj < 8; ++jj) dots[jj] = 0.f;
#pragma unroll 4
        for (int d = 0; d < 64; ++d) {
            float qd = Qs[r][d];
#pragma unroll
            for (int jj = 0; jj < 8; ++jj) dots[jj] += qd * Ks[g * 8 + jj][d];
        }
        float pmax = -INFINITY;
#pragma unroll
        for (int jj = 0; jj < 8; ++jj) {
            int j = g * 8 + jj;
            float sv = (k0 + j <= q0 + r) ? dots[jj] : -INFINITY;
            Ss[r][j] = sv;
            pmax = fmaxf(pmax, sv);
        }
        red[r][g] = pmax;
        __syncthreads();
        float tmax = fmaxf(fmaxf(red[r][0], red[r][1]), fmaxf(red[r][2], red[r][3]));
        float m_new = fmaxf(m_old, tmax);
        float alpha = expf(m_old - m_new);   // exp(-inf)=0 on first tile
        float psum = 0.f;
#pragma unroll
        for (int jj = 0; jj < 8; ++jj) {
            int j = g * 8 + jj;
            float p = expf(Ss[r][j] - m_new);
            Ss[r][j] = p;
            psum += p;
        }
        red[r][g + 4] = psum;
        __syncthreads();
        float tsum = red[r][4] + red[r][5] + red[r][6] + red[r][7];
        l = l * alpha + tsum;
        m_old = m_new;
#pragma unroll
        for (int u = 0; u < 16; ++u) O[u] *= alpha;
#pragma unroll 4
        for (int j = 0; j < 32; ++j) {
            float p = Ss[r][j];
#pragma unroll
            for (int u = 0; u < 16; ++u) O[u] += p * Vs[j][g * 16 + u];
        }
    }
    // write out (bf16) + o_sq partial
    float inv = 1.f / l;
    __hip_bfloat16* orow = out + (size_t)(b * TT + q0 + r) * CC + h * DD + g * 16;
    float part = 0.f;
#pragma unroll
    for (int u = 0; u < 16; ++u) {
        float o = O[u] * inv;
        part += o * o;
        orow[u] = (__hip_bfloat16)o;
    }
    atomicAdd(&osq[b * TT + q0 + r], part);
}

// ---------------------------------------------------------------- launcher
extern "C" void kernel_launch(void* const* d_in, const int* in_sizes, int n_in,
                              void* d_out, int out_size, void* d_ws, size_t ws_size,
                              hipStream_t stream) {
    const float* x      = (const float*)d_in[0];
    // d_in[1] = mask (causal tril) — implied analytically, unused
    const float* w_attn = (const float*)d_in[2];
    const float* b_attn = (const float*)d_in[3];
    const float* w_proj = (const float*)d_in[4];
    const float* b_proj = (const float*)d_in[5];
    float* out = (float*)d_out;

    char* ws = (char*)d_ws;
    float*          qkv  = (float*)(ws + 0);                  // 4096x3072 fp32
    __hip_bfloat16* xbf  = (__hip_bfloat16*)(ws + 50331648);  // 4096x1024 bf16
    __hip_bfloat16* aout = (__hip_bfloat16*)(ws + 58720256);  // 4096x1024 bf16
    __hip_bfloat16* watT = (__hip_bfloat16*)(ws + 67108864);  // 3072x1024 bf16
    __hip_bfloat16* wpT  = (__hip_bfloat16*)(ws + 73400320);  // 1024x1024 bf16
    float*          rope = (float*)(ws + 75497472);           // 2048x32x2 fp32
    float*          xsq  = (float*)(ws + 76021760);           // 4096
    float*          osq  = (float*)(ws + 76038144);           // 4096
    float*          wsqa = (float*)(ws + 76054528);           // 3072
    float*          wsqp = (float*)(ws + 76066816);           // 1024

    float scale1 = (float)(sqrt(3072.0) / log1p(3072.0));
    float scale2 = (float)(sqrt(1024.0) / log1p(1024.0));

    hipMemsetAsync(wsqa, 0, 3072 * 4, stream);
    hipMemsetAsync(wsqp, 0, 1024 * 4, stream);
    hipMemsetAsync(osq, 0, ROWS * 4, stream);

    rope_init<<<256, 256, 0, stream>>>(rope);
    rowsq_cast<<<ROWS, 256, 0, stream>>>(x, xsq, xbf);
    transpose_colsq<<<dim3(N1 / 64, CC / 64), 256, 0, stream>>>(w_attn, watT, wsqa, CC, N1);
    transpose_colsq<<<dim3(CC / 64, CC / 64), 256, 0, stream>>>(w_proj, wpT, wsqp, CC, CC);
    yat_gemm<<<dim3(N1 / 64, ROWS / 64), 256, 0, stream>>>(xbf, watT, xsq, wsqa, b_attn,
                                                           qkv, ROWS, N1, CC, scale1);
    attn_kernel<<<dim3(32, HH, BB), 256, 0, stream>>>(qkv, rope, aout, osq);
    yat_gemm<<<dim3(CC / 64, ROWS / 64), 256, 0, stream>>>(aout, wpT, osq, wsqp, b_proj,
                                                           out, ROWS, CC, CC, scale2);
}

// Round 2
// 334.416 us; speedup vs baseline: 4.7534x; 4.7534x over previous
//
#include <hip/hip_runtime.h>
#include <hip/hip_bf16.h>
#include <cmath>

// Problem constants
#define BB 2
#define TT 2048
#define CC 1024
#define HH 16
#define DD 64
#define ROWS (BB*TT)          // 4096
#define N1 (3*CC)             // 3072
#define EPS 1e-6f

using short8 = __attribute__((ext_vector_type(8))) short;
using f32x4  = __attribute__((ext_vector_type(4))) float;

// ---------------------------------------------------------------- rope table
// rope[pos*64 + 2*i] = cos(pos*freq_i), +1 = sin. freq_i = 10000^(-i/32)
__global__ void rope_init(float* __restrict__ rope) {
    int idx = blockIdx.x * 256 + threadIdx.x;      // 0 .. T*32-1
    if (idx >= TT * 32) return;
    int t = idx >> 5, i = idx & 31;
    double freq = pow(10000.0, -(double)i / 32.0);
    float ang = (float)t * (float)freq;
    rope[idx * 2 + 0] = cosf(ang);
    rope[idx * 2 + 1] = sinf(ang);
}

// ------------------------------------------- row sum-of-squares + bf16 cast
__global__ void rowsq_cast(const float* __restrict__ X, float* __restrict__ xsq,
                           __hip_bfloat16* __restrict__ Xb) {
    int row = blockIdx.x;
    int t = threadIdx.x;
    const float* xr = X + (size_t)row * CC;
    __hip_bfloat16* br = Xb + (size_t)row * CC;
    float p = 0.f;
#pragma unroll
    for (int i = 0; i < 4; ++i) {
        float v = xr[t + i * 256];
        p += v * v;
        br[t + i * 256] = (__hip_bfloat16)v;
    }
    __shared__ float s[256];
    s[t] = p;
    __syncthreads();
    for (int off = 128; off > 0; off >>= 1) {
        if (t < off) s[t] += s[t + off];
        __syncthreads();
    }
    if (t == 0) xsq[row] = s[0];
}

// --------------------- transpose W (K x N fp32) -> Wt (N x K bf16) + col sq
__global__ void transpose_colsq(const float* __restrict__ W,
                                __hip_bfloat16* __restrict__ Wt,
                                float* __restrict__ wsq, int K, int N) {
    __shared__ unsigned short tile[64][65];
    int n0 = blockIdx.x * 64, k0 = blockIdx.y * 64;
    int c = threadIdx.x & 63, rg = threadIdx.x >> 6;
    float part = 0.f;
#pragma unroll
    for (int rr = 0; rr < 16; ++rr) {
        int r = rg + rr * 4;
        float f = W[(size_t)(k0 + r) * N + n0 + c];
        __hip_bfloat16 h = (__hip_bfloat16)f;
        tile[r][c] = *(unsigned short*)&h;
        part += f * f;
    }
    atomicAdd(&wsq[n0 + c], part);
    __syncthreads();
#pragma unroll
    for (int rr = 0; rr < 16; ++rr) {
        int r = rg + rr * 4;
        unsigned short u = tile[c][r];
        Wt[(size_t)(n0 + r) * K + k0 + c] = *(__hip_bfloat16*)&u;
    }
}

// ----------------------------------------- MFMA bf16 GEMM with yat epilogue
__global__ __launch_bounds__(256) void yat_gemm(
    const __hip_bfloat16* __restrict__ A,
    const __hip_bfloat16* __restrict__ Bt,
    const float* __restrict__ xsq, const float* __restrict__ wsq,
    const float* __restrict__ bias, float* __restrict__ C,
    int M, int N, int K, float scale) {
    __shared__ __align__(16) unsigned short As[64 * 32];
    __shared__ __align__(16) unsigned short Bs[64 * 32];
    int tid = threadIdx.x;
    int wave = tid >> 6, lane = tid & 63;
    int quad = lane >> 4, l16 = lane & 15;
    int m0 = blockIdx.y * 64, n0 = blockIdx.x * 64;

    f32x4 acc[4] = {};
    int ar = tid >> 2;              // staging row 0..63
    int ak = (tid & 3) << 3;        // staging k offset 0/8/16/24
    const __hip_bfloat16* Ap = A + (size_t)(m0 + ar) * K + ak;
    const __hip_bfloat16* Bp = Bt + (size_t)(n0 + ar) * K + ak;

    for (int k0 = 0; k0 < K; k0 += 32) {
        uint4 av = *(const uint4*)(Ap + k0);
        uint4 bv = *(const uint4*)(Bp + k0);
        __syncthreads();
        *(uint4*)(As + tid * 8) = av;
        *(uint4*)(Bs + tid * 8) = bv;
        __syncthreads();
        short8 afrag = *(const short8*)(As + (wave * 16 + l16) * 32 + quad * 8);
#pragma unroll
        for (int nb = 0; nb < 4; ++nb) {
            short8 bfrag = *(const short8*)(Bs + (nb * 16 + l16) * 32 + quad * 8);
            acc[nb] = __builtin_amdgcn_mfma_f32_16x16x32_bf16(afrag, bfrag, acc[nb], 0, 0, 0);
        }
    }
    int mbase = m0 + wave * 16 + quad * 4;
#pragma unroll
    for (int nb = 0; nb < 4; ++nb) {
        int col = n0 + nb * 16 + l16;
        float wq = wsq[col];
        float bs = bias[col];
#pragma unroll
        for (int r = 0; r < 4; ++r) {
            int row = mbase + r;
            float dot = acc[nb][r];
            float dist = xsq[row] + wq - 2.f * dot + EPS;
            float y = dot * dot / dist * scale + bs;
            C[(size_t)row * N + col] = y;
        }
    }
}

// ---------------------------------------------- prep: qkv fp32 -> bf16 Q,K,V^T
// Qb[b,h,t,d] (rope, *0.125), Kb[b,h,t,d] (rope), Vtb[b,h,d,t]
__global__ __launch_bounds__(256) void prep_qkv(
    const float* __restrict__ qkv, const float* __restrict__ rope,
    __hip_bfloat16* __restrict__ Qb, __hip_bfloat16* __restrict__ Kb,
    __hip_bfloat16* __restrict__ Vtb) {
    int t0 = blockIdx.x * 64;
    int h = blockIdx.y, b = blockIdx.z;
    int bh = b * HH + h;
    int tid = threadIdx.x;
    __shared__ float vt[64][65];
    int r = tid >> 2, g = tid & 3;
    int t = t0 + r;
    const float* base = qkv + (size_t)(b * TT + t) * N1 + h * DD;
    const float* rp = rope + (size_t)t * 64;
    __hip_bfloat16* qd = Qb + ((size_t)bh * TT + t) * DD;
    __hip_bfloat16* kd = Kb + ((size_t)bh * TT + t) * DD;
#pragma unroll
    for (int u = 0; u < 8; ++u) {
        int d0 = g * 16 + u * 2;
        int i = d0 >> 1;
        float cs = rp[2 * i], sn = rp[2 * i + 1];
        float q0v = base[d0], q1v = base[d0 + 1];
        qd[d0]     = (__hip_bfloat16)((q0v * cs - q1v * sn) * 0.125f);
        qd[d0 + 1] = (__hip_bfloat16)((q1v * cs + q0v * sn) * 0.125f);
        float k0v = base[CC + d0], k1v = base[CC + d0 + 1];
        kd[d0]     = (__hip_bfloat16)(k0v * cs - k1v * sn);
        kd[d0 + 1] = (__hip_bfloat16)(k1v * cs + k0v * sn);
    }
#pragma unroll
    for (int u = 0; u < 4; ++u) {
        float4 v = *(const float4*)(base + 2 * CC + g * 16 + u * 4);
        vt[r][g * 16 + u * 4 + 0] = v.x;
        vt[r][g * 16 + u * 4 + 1] = v.y;
        vt[r][g * 16 + u * 4 + 2] = v.z;
        vt[r][g * 16 + u * 4 + 3] = v.w;
    }
    __syncthreads();
    // write transposed: this thread owns d = r, t range t0+g*16..+15
    __hip_bfloat16* vd = Vtb + ((size_t)bh * DD + r) * TT + t0 + g * 16;
#pragma unroll
    for (int u = 0; u < 16; ++u) vd[u] = (__hip_bfloat16)vt[g * 16 + u][r];
}

// ------------------------------------------------ MFMA flash attention
// grid (32 qblk reversed, H, B), block 256 (4 waves); wave owns 16 q rows.
__global__ __launch_bounds__(256) void attn_mfma(
    const __hip_bfloat16* __restrict__ Qb, const __hip_bfloat16* __restrict__ Kb,
    const __hip_bfloat16* __restrict__ Vtb,
    __hip_bfloat16* __restrict__ out, float* __restrict__ osq) {
    int qblk = 31 - (int)blockIdx.x;     // heavy blocks first
    int h = blockIdx.y, b = blockIdx.z, bh = b * HH + h;
    int q0 = qblk * 64;
    int tid = threadIdx.x;
    int wave = tid >> 6, lane = tid & 63, quad = lane >> 4, l16 = lane & 15;

    __shared__ __align__(16) unsigned short Qs[64 * 72];
    __shared__ __align__(16) unsigned short Ks[64 * 72];
    __shared__ __align__(16) unsigned short Vs[64 * 72];   // V^T: [d][key]
    __shared__ __align__(16) unsigned short Ps[4 * 16 * 72];

    int r = tid >> 2, g = tid & 3;
    {   // stage Q tile (bf16, rope'd, pre-scaled)
        const uint4* src = (const uint4*)(Qb + ((size_t)bh * TT + q0 + r) * DD + g * 16);
        uint4 a0 = src[0], a1 = src[1];
        *(uint4*)(Qs + r * 72 + g * 16) = a0;
        *(uint4*)(Qs + r * 72 + g * 16 + 8) = a1;
    }
    __syncthreads();
    short8 afQ0 = *(const short8*)(Qs + (wave * 16 + l16) * 72 + quad * 8);
    short8 afQ1 = *(const short8*)(Qs + (wave * 16 + l16) * 72 + 32 + quad * 8);

    f32x4 acc_o[4] = {};
    float mrow[4] = {-INFINITY, -INFINITY, -INFINITY, -INFINITY};
    float lrow[4] = {0.f, 0.f, 0.f, 0.f};

    const __hip_bfloat16* Kbase = Kb + (size_t)bh * TT * DD;
    const __hip_bfloat16* Vbase = Vtb + (size_t)bh * DD * TT;

    int ntiles = qblk + 1;
    for (int kt = 0; kt < ntiles; ++kt) {
        int k0 = kt * 64;
        const uint4* ksrc = (const uint4*)(Kbase + (size_t)(k0 + r) * DD + g * 16);
        uint4 kv0 = ksrc[0], kv1 = ksrc[1];
        const uint4* vsrc = (const uint4*)(Vbase + (size_t)r * TT + k0 + g * 16);
        uint4 vv0 = vsrc[0], vv1 = vsrc[1];
        __syncthreads();
        *(uint4*)(Ks + r * 72 + g * 16) = kv0;
        *(uint4*)(Ks + r * 72 + g * 16 + 8) = kv1;
        *(uint4*)(Vs + r * 72 + g * 16) = vv0;
        *(uint4*)(Vs + r * 72 + g * 16 + 8) = vv1;
        __syncthreads();

        // S = Q K^T for this wave's 16 rows x 64 keys
        f32x4 acc_s[4];
#pragma unroll
        for (int nb = 0; nb < 4; ++nb) {
            short8 bf0 = *(const short8*)(Ks + (nb * 16 + l16) * 72 + quad * 8);
            short8 bf1 = *(const short8*)(Ks + (nb * 16 + l16) * 72 + 32 + quad * 8);
            f32x4 z = {0.f, 0.f, 0.f, 0.f};
            z = __builtin_amdgcn_mfma_f32_16x16x32_bf16(afQ0, bf0, z, 0, 0, 0);
            acc_s[nb] = __builtin_amdgcn_mfma_f32_16x16x32_bf16(afQ1, bf1, z, 0, 0, 0);
        }
        bool last = (kt == qblk);
        int row_local = wave * 16 + quad * 4;   // + ri
        float pm[4] = {-INFINITY, -INFINITY, -INFINITY, -INFINITY};
#pragma unroll
        for (int nb = 0; nb < 4; ++nb) {
            int col_local = nb * 16 + l16;
#pragma unroll
            for (int ri = 0; ri < 4; ++ri) {
                float sv = acc_s[nb][ri];
                if (last && col_local > row_local + ri) sv = -INFINITY;
                acc_s[nb][ri] = sv;
                pm[ri] = fmaxf(pm[ri], sv);
            }
        }
#pragma unroll
        for (int off = 1; off < 16; off <<= 1) {
#pragma unroll
            for (int ri = 0; ri < 4; ++ri)
                pm[ri] = fmaxf(pm[ri], __shfl_xor(pm[ri], off, 64));
        }
        float alpha[4], rs[4];
#pragma unroll
        for (int ri = 0; ri < 4; ++ri) {
            float mn = fmaxf(mrow[ri], pm[ri]);
            alpha[ri] = __expf(mrow[ri] - mn);
            mrow[ri] = mn;
            rs[ri] = 0.f;
        }
#pragma unroll
        for (int nb = 0; nb < 4; ++nb) {
#pragma unroll
            for (int ri = 0; ri < 4; ++ri) {
                float p = __expf(acc_s[nb][ri] - mrow[ri]);
                rs[ri] += p;
                __hip_bfloat16 hp = (__hip_bfloat16)p;
                Ps[wave * 1152 + (quad * 4 + ri) * 72 + nb * 16 + l16] = *(unsigned short*)&hp;
            }
        }
#pragma unroll
        for (int off = 1; off < 16; off <<= 1) {
#pragma unroll
            for (int ri = 0; ri < 4; ++ri)
                rs[ri] += __shfl_xor(rs[ri], off, 64);
        }
#pragma unroll
        for (int ri = 0; ri < 4; ++ri) lrow[ri] = lrow[ri] * alpha[ri] + rs[ri];
#pragma unroll
        for (int nb2 = 0; nb2 < 4; ++nb2) {
#pragma unroll
            for (int ri = 0; ri < 4; ++ri) acc_o[nb2][ri] *= alpha[ri];
        }
        // P*V (per-wave P strip round-trips via LDS into A-layout)
        short8 afP0 = *(const short8*)(Ps + wave * 1152 + l16 * 72 + quad * 8);
        short8 afP1 = *(const short8*)(Ps + wave * 1152 + l16 * 72 + 32 + quad * 8);
#pragma unroll
        for (int nb2 = 0; nb2 < 4; ++nb2) {
            short8 bv0 = *(const short8*)(Vs + (nb2 * 16 + l16) * 72 + quad * 8);
            short8 bv1 = *(const short8*)(Vs + (nb2 * 16 + l16) * 72 + 32 + quad * 8);
            acc_o[nb2] = __builtin_amdgcn_mfma_f32_16x16x32_bf16(afP0, bv0, acc_o[nb2], 0, 0, 0);
            acc_o[nb2] = __builtin_amdgcn_mfma_f32_16x16x32_bf16(afP1, bv1, acc_o[nb2], 0, 0, 0);
        }
    }
    // epilogue: normalize, write bf16 out + osq row partials
    int row = q0 + wave * 16 + quad * 4;    // + ri
#pragma unroll
    for (int ri = 0; ri < 4; ++ri) {
        float inv = 1.f / lrow[ri];
        float part = 0.f;
        __hip_bfloat16* orow = out + ((size_t)(b * TT) + row + ri) * CC + h * DD;
#pragma unroll
        for (int nb2 = 0; nb2 < 4; ++nb2) {
            float o = acc_o[nb2][ri] * inv;
            part += o * o;
            orow[nb2 * 16 + l16] = (__hip_bfloat16)o;
        }
#pragma unroll
        for (int off = 1; off < 16; off <<= 1) part += __shfl_xor(part, off, 64);
        if (l16 == 0) atomicAdd(&osq[b * TT + row + ri], part);
    }
}

// ---------------------------------------------------------------- launcher
extern "C" void kernel_launch(void* const* d_in, const int* in_sizes, int n_in,
                              void* d_out, int out_size, void* d_ws, size_t ws_size,
                              hipStream_t stream) {
    const float* x      = (const float*)d_in[0];
    // d_in[1] = mask (causal tril) — implied analytically, unused
    const float* w_attn = (const float*)d_in[2];
    const float* b_attn = (const float*)d_in[3];
    const float* w_proj = (const float*)d_in[4];
    const float* b_proj = (const float*)d_in[5];
    float* out = (float*)d_out;

    char* ws = (char*)d_ws;
    float*          qkv  = (float*)(ws + 0);                  // 4096x3072 fp32
    __hip_bfloat16* xbf  = (__hip_bfloat16*)(ws + 50331648);  // 4096x1024 bf16
    __hip_bfloat16* aout = (__hip_bfloat16*)(ws + 58720256);  // 4096x1024 bf16
    __hip_bfloat16* watT = (__hip_bfloat16*)(ws + 67108864);  // 3072x1024 bf16
    __hip_bfloat16* wpT  = (__hip_bfloat16*)(ws + 73400320);  // 1024x1024 bf16
    float*          rope = (float*)(ws + 75497472);           // 2048x32x2 fp32
    float*          xsq  = (float*)(ws + 76021760);           // 4096
    float*          osq  = (float*)(ws + 76038144);           // 4096
    float*          wsqa = (float*)(ws + 76054528);           // 3072
    float*          wsqp = (float*)(ws + 76066816);           // 1024
    __hip_bfloat16* Qb   = (__hip_bfloat16*)(ws + 76070912);  // [b,h,t,d] 8MB
    __hip_bfloat16* Kb   = (__hip_bfloat16*)(ws + 84459520);  // [b,h,t,d] 8MB
    __hip_bfloat16* Vtb  = (__hip_bfloat16*)(ws + 92848128);  // [b,h,d,t] 8MB

    float scale1 = (float)(sqrt(3072.0) / log1p(3072.0));
    float scale2 = (float)(sqrt(1024.0) / log1p(1024.0));

    hipMemsetAsync(wsqa, 0, 3072 * 4, stream);
    hipMemsetAsync(wsqp, 0, 1024 * 4, stream);
    hipMemsetAsync(osq, 0, ROWS * 4, stream);

    rope_init<<<256, 256, 0, stream>>>(rope);
    rowsq_cast<<<ROWS, 256, 0, stream>>>(x, xsq, xbf);
    transpose_colsq<<<dim3(N1 / 64, CC / 64), 256, 0, stream>>>(w_attn, watT, wsqa, CC, N1);
    transpose_colsq<<<dim3(CC / 64, CC / 64), 256, 0, stream>>>(w_proj, wpT, wsqp, CC, CC);
    yat_gemm<<<dim3(N1 / 64, ROWS / 64), 256, 0, stream>>>(xbf, watT, xsq, wsqa, b_attn,
                                                           qkv, ROWS, N1, CC, scale1);
    prep_qkv<<<dim3(TT / 64, HH, BB), 256, 0, stream>>>(qkv, rope, Qb, Kb, Vtb);
    attn_mfma<<<dim3(32, HH, BB), 256, 0, stream>>>(Qb, Kb, Vtb, aout, osq);
    yat_gemm<<<dim3(CC / 64, ROWS / 64), 256, 0, stream>>>(aout, wpT, osq, wsqp, b_proj,
                                                           out, ROWS, CC, CC, scale2);
}

// Round 3
// 279.065 us; speedup vs baseline: 5.6961x; 1.1983x over previous
//
#include <hip/hip_runtime.h>
#include <hip/hip_bf16.h>
#include <cmath>

// Problem constants
#define BB 2
#define TT 2048
#define CC 1024
#define HH 16
#define DD 64
#define ROWS (BB*TT)          // 4096
#define N1 (3*CC)             // 3072
#define EPS 1e-6f

using short8 = __attribute__((ext_vector_type(8))) short;
using f32x4  = __attribute__((ext_vector_type(4))) float;

__device__ __forceinline__ void gl_lds16(const __hip_bfloat16* g, unsigned short* l) {
    __builtin_amdgcn_global_load_lds(
        (const __attribute__((address_space(1))) unsigned int*)(g),
        (__attribute__((address_space(3))) unsigned int*)(l), 16, 0, 0);
}

__device__ __forceinline__ unsigned int bf16pair(float a, float b) {
    __hip_bfloat16 ha = (__hip_bfloat16)a, hb = (__hip_bfloat16)b;  // RNE
    unsigned short ua = *(unsigned short*)&ha, ub = *(unsigned short*)&hb;
    return (unsigned int)ua | ((unsigned int)ub << 16);
}

// ---------------------------------------------------------------- rope table
__global__ void rope_init(float* __restrict__ rope) {
    int idx = blockIdx.x * 256 + threadIdx.x;      // 0 .. T*32-1
    if (idx >= TT * 32) return;
    int t = idx >> 5, i = idx & 31;
    double freq = pow(10000.0, -(double)i / 32.0);
    float ang = (float)t * (float)freq;
    rope[idx * 2 + 0] = cosf(ang);
    rope[idx * 2 + 1] = sinf(ang);
}

// ------------------------------------------- row sum-of-squares + bf16 cast
__global__ void rowsq_cast(const float* __restrict__ X, float* __restrict__ xsq,
                           __hip_bfloat16* __restrict__ Xb) {
    int row = blockIdx.x;
    int t = threadIdx.x;
    const float* xr = X + (size_t)row * CC;
    __hip_bfloat16* br = Xb + (size_t)row * CC;
    float p = 0.f;
#pragma unroll
    for (int i = 0; i < 4; ++i) {
        float v = xr[t + i * 256];
        p += v * v;
        br[t + i * 256] = (__hip_bfloat16)v;
    }
    __shared__ float s[256];
    s[t] = p;
    __syncthreads();
    for (int off = 128; off > 0; off >>= 1) {
        if (t < off) s[t] += s[t + off];
        __syncthreads();
    }
    if (t == 0) xsq[row] = s[0];
}

// --------------------- transpose W (K x N fp32) -> Wt (N x K bf16) + col sq
__global__ void transpose_colsq(const float* __restrict__ W,
                                __hip_bfloat16* __restrict__ Wt,
                                float* __restrict__ wsq, int K, int N) {
    __shared__ unsigned short tile[64][65];
    int n0 = blockIdx.x * 64, k0 = blockIdx.y * 64;
    int c = threadIdx.x & 63, rg = threadIdx.x >> 6;
    float part = 0.f;
#pragma unroll
    for (int rr = 0; rr < 16; ++rr) {
        int r = rg + rr * 4;
        float f = W[(size_t)(k0 + r) * N + n0 + c];
        __hip_bfloat16 h = (__hip_bfloat16)f;
        tile[r][c] = *(unsigned short*)&h;
        part += f * f;
    }
    atomicAdd(&wsq[n0 + c], part);
    __syncthreads();
#pragma unroll
    for (int rr = 0; rr < 16; ++rr) {
        int r = rg + rr * 4;
        unsigned short u = tile[c][r];
        Wt[(size_t)(n0 + r) * K + k0 + c] = *(__hip_bfloat16*)&u;
    }
}

// ------------------- m97-style MFMA bf16 GEMM (TMxTN tile) with yat epilogue
// C[M][N] fp32 = yat( A[M][K] bf16 * Bt[N][K]^T )
template<int TM, int TN>
__global__ __launch_bounds__(256) void yat_gemm_big(
    const __hip_bfloat16* __restrict__ A,
    const __hip_bfloat16* __restrict__ Bt,
    const float* __restrict__ xsq, const float* __restrict__ wsq,
    const float* __restrict__ bias, float* __restrict__ C,
    int M, int N, int K, float scale) {
    constexpr int MT = TM / 32;       // 16x16 tiles per wave (rows)
    constexpr int NT = TN / 32;       // 16x16 tiles per wave (cols)
    constexpr int IA = TM / 64;       // global_load_lds insts per wave (A)
    constexpr int IB = TN / 64;
    __shared__ __align__(16) unsigned short As[TM * 32];
    __shared__ __align__(16) unsigned short Bs[TN * 32];
    int tid = threadIdx.x;
    int wave = tid >> 6, lane = tid & 63, quad = lane >> 4, l16 = lane & 15;
    int wr = wave >> 1, wc = wave & 1;
    int m0 = blockIdx.y * TM, n0 = blockIdx.x * TN;

    f32x4 acc[MT][NT];
#pragma unroll
    for (int mt = 0; mt < MT; ++mt)
#pragma unroll
        for (int nt = 0; nt < NT; ++nt) acc[mt][nt] = f32x4{0.f, 0.f, 0.f, 0.f};

    int lrow = lane >> 2, lk = (lane & 3) << 3;
    for (int k0 = 0; k0 < K; k0 += 32) {
        __syncthreads();
#pragma unroll
        for (int i = 0; i < IA; ++i)
            gl_lds16(A + (size_t)(m0 + (wave * IA + i) * 16 + lrow) * K + k0 + lk,
                     As + (wave * IA + i) * 512);
#pragma unroll
        for (int i = 0; i < IB; ++i)
            gl_lds16(Bt + (size_t)(n0 + (wave * IB + i) * 16 + lrow) * K + k0 + lk,
                     Bs + (wave * IB + i) * 512);
        __syncthreads();
        short8 af[MT], bf[NT];
#pragma unroll
        for (int mt = 0; mt < MT; ++mt)
            af[mt] = *(const short8*)(As + (wr * (TM / 2) + mt * 16 + l16) * 32 + quad * 8);
#pragma unroll
        for (int nt = 0; nt < NT; ++nt)
            bf[nt] = *(const short8*)(Bs + (wc * (TN / 2) + nt * 16 + l16) * 32 + quad * 8);
#pragma unroll
        for (int mt = 0; mt < MT; ++mt)
#pragma unroll
            for (int nt = 0; nt < NT; ++nt)
                acc[mt][nt] = __builtin_amdgcn_mfma_f32_16x16x32_bf16(af[mt], bf[nt], acc[mt][nt], 0, 0, 0);
    }
    int mb = m0 + wr * (TM / 2) + quad * 4;
#pragma unroll
    for (int nt = 0; nt < NT; ++nt) {
        int col = n0 + wc * (TN / 2) + nt * 16 + l16;
        float wq = wsq[col];
        float bs = bias[col];
#pragma unroll
        for (int mt = 0; mt < MT; ++mt) {
#pragma unroll
            for (int r = 0; r < 4; ++r) {
                int row = mb + mt * 16 + r;
                float dot = acc[mt][nt][r];
                float dist = xsq[row] + wq - 2.f * dot + EPS;
                C[(size_t)row * N + col] = dot * dot / dist * scale + bs;
            }
        }
    }
}

// ---------------------------------------------- prep: qkv fp32 -> bf16 Q,K,V^T
__global__ __launch_bounds__(256) void prep_qkv(
    const float* __restrict__ qkv, const float* __restrict__ rope,
    __hip_bfloat16* __restrict__ Qb, __hip_bfloat16* __restrict__ Kb,
    __hip_bfloat16* __restrict__ Vtb) {
    int t0 = blockIdx.x * 64;
    int h = blockIdx.y, b = blockIdx.z;
    int bh = b * HH + h;
    int tid = threadIdx.x;
    __shared__ float vt[64][65];
    int r = tid >> 2, g = tid & 3;
    int t = t0 + r;
    const float* base = qkv + (size_t)(b * TT + t) * N1 + h * DD;
    const float* rp = rope + (size_t)t * 64;
    __hip_bfloat16* qd = Qb + ((size_t)bh * TT + t) * DD;
    __hip_bfloat16* kd = Kb + ((size_t)bh * TT + t) * DD;
#pragma unroll
    for (int u = 0; u < 8; ++u) {
        int d0 = g * 16 + u * 2;
        int i = d0 >> 1;
        float cs = rp[2 * i], sn = rp[2 * i + 1];
        float q0v = base[d0], q1v = base[d0 + 1];
        qd[d0]     = (__hip_bfloat16)((q0v * cs - q1v * sn) * 0.125f);
        qd[d0 + 1] = (__hip_bfloat16)((q1v * cs + q0v * sn) * 0.125f);
        float k0v = base[CC + d0], k1v = base[CC + d0 + 1];
        kd[d0]     = (__hip_bfloat16)(k0v * cs - k1v * sn);
        kd[d0 + 1] = (__hip_bfloat16)(k1v * cs + k0v * sn);
    }
#pragma unroll
    for (int u = 0; u < 4; ++u) {
        float4 v = *(const float4*)(base + 2 * CC + g * 16 + u * 4);
        vt[r][g * 16 + u * 4 + 0] = v.x;
        vt[r][g * 16 + u * 4 + 1] = v.y;
        vt[r][g * 16 + u * 4 + 2] = v.z;
        vt[r][g * 16 + u * 4 + 3] = v.w;
    }
    __syncthreads();
    __hip_bfloat16* vd = Vtb + ((size_t)bh * DD + r) * TT + t0 + g * 16;
#pragma unroll
    for (int u = 0; u < 16; ++u) vd[u] = (__hip_bfloat16)vt[g * 16 + u][r];
}

// ------------------------------------------------ barrier-free MFMA attention
// S^T = K·Q^T (A=K rows, B=Q rows), O^T = V^T·P^T (A=V^T rows, B=P rows).
// Wave owns 32 q-rows (2 strips of 16); block = 4 waves = 128 rows.
// K/V frags read direct from global (L1-shared); P via wave-private LDS strip.
__global__ __launch_bounds__(256, 2) void attn_mfma2(
    const __hip_bfloat16* __restrict__ Qb, const __hip_bfloat16* __restrict__ Kb,
    const __hip_bfloat16* __restrict__ Vtb,
    __hip_bfloat16* __restrict__ out, float* __restrict__ osq) {
    int idx = blockIdx.x;
    // pair heavy+light blocks per CU: first 256 blocks qblk 15..8, rest 0..7
    int qblk = (idx < 256) ? (15 - (idx >> 5)) : ((idx - 256) >> 5);
    int bh = idx & 31;
    int b = bh >> 4, h = bh & 15;
    int tid = threadIdx.x;
    int wave = tid >> 6, lane = tid & 63, quad = lane >> 4, l16 = lane & 15;

    __shared__ __align__(16) unsigned short Ps[4][16 * 72];   // per-wave strip

    const __hip_bfloat16* Qbase = Qb + (size_t)bh * TT * DD;
    const __hip_bfloat16* Kbase = Kb + (size_t)bh * TT * DD;
    const __hip_bfloat16* Vbase = Vtb + (size_t)bh * DD * TT;

    int qw = qblk * 128 + wave * 32;     // wave's first q row
    short8 qf[2][2];
#pragma unroll
    for (int s = 0; s < 2; ++s) {
        const __hip_bfloat16* qr = Qbase + (size_t)(qw + s * 16 + l16) * DD + quad * 8;
        qf[s][0] = *(const short8*)(qr);
        qf[s][1] = *(const short8*)(qr + 32);
    }
    f32x4 acc_o[2][4];
#pragma unroll
    for (int s = 0; s < 2; ++s)
#pragma unroll
        for (int mt = 0; mt < 4; ++mt) acc_o[s][mt] = f32x4{0.f, 0.f, 0.f, 0.f};
    float rs[2] = {0.f, 0.f};

    unsigned short* pp = &Ps[wave][0];
    int ntiles = 2 * qblk + 1 + (wave >> 1);
    for (int kt = 0; kt < ntiles; ++kt) {
        int k0 = kt * 64;
        short8 kf[4][2], vf[4][2];
#pragma unroll
        for (int mt = 0; mt < 4; ++mt) {
            const __hip_bfloat16* kr = Kbase + (size_t)(k0 + mt * 16 + l16) * DD + quad * 8;
            kf[mt][0] = *(const short8*)(kr);
            kf[mt][1] = *(const short8*)(kr + 32);
            const __hip_bfloat16* vr = Vbase + (size_t)(mt * 16 + l16) * TT + k0 + quad * 8;
            vf[mt][0] = *(const short8*)(vr);
            vf[mt][1] = *(const short8*)(vr + 32);
        }
#pragma unroll
        for (int s = 0; s < 2; ++s) {
            int qs0 = qw + s * 16;
            f32x4 accs[4];
#pragma unroll
            for (int mt = 0; mt < 4; ++mt) {
                f32x4 z = {0.f, 0.f, 0.f, 0.f};
                z = __builtin_amdgcn_mfma_f32_16x16x32_bf16(kf[mt][0], qf[s][0], z, 0, 0, 0);
                accs[mt] = __builtin_amdgcn_mfma_f32_16x16x32_bf16(kf[mt][1], qf[s][1], z, 0, 0, 0);
            }
            bool needmask = (k0 + 63 > qs0);
            int q_g = qs0 + l16;
#pragma unroll
            for (int mt = 0; mt < 4; ++mt) {
                float p0, p1, p2, p3;
                {
                    int keyb = k0 + mt * 16 + quad * 4;
                    float e0 = __expf(accs[mt][0]);
                    float e1 = __expf(accs[mt][1]);
                    float e2 = __expf(accs[mt][2]);
                    float e3 = __expf(accs[mt][3]);
                    p0 = (!needmask || keyb + 0 <= q_g) ? e0 : 0.f;
                    p1 = (!needmask || keyb + 1 <= q_g) ? e1 : 0.f;
                    p2 = (!needmask || keyb + 2 <= q_g) ? e2 : 0.f;
                    p3 = (!needmask || keyb + 3 <= q_g) ? e3 : 0.f;
                }
                rs[s] += p0 + p1 + p2 + p3;
                uint2 w2;
                w2.x = bf16pair(p0, p1);
                w2.y = bf16pair(p2, p3);
                *(uint2*)(pp + l16 * 72 + mt * 16 + quad * 4) = w2;   // P[q=l16][key]
            }
            // read P as B-operand (row-major [q][k]); wave-private, in-order DS pipe
            short8 pf0 = *(const short8*)(pp + l16 * 72 + quad * 8);
            short8 pf1 = *(const short8*)(pp + l16 * 72 + 32 + quad * 8);
#pragma unroll
            for (int mt = 0; mt < 4; ++mt) {
                acc_o[s][mt] = __builtin_amdgcn_mfma_f32_16x16x32_bf16(vf[mt][0], pf0, acc_o[s][mt], 0, 0, 0);
                acc_o[s][mt] = __builtin_amdgcn_mfma_f32_16x16x32_bf16(vf[mt][1], pf1, acc_o[s][mt], 0, 0, 0);
            }
        }
    }
    // epilogue per strip: normalize, osq, transpose via wave-private LDS, store
#pragma unroll
    for (int s = 0; s < 2; ++s) {
        float l = rs[s];
        l += __shfl_xor(l, 16, 64);
        l += __shfl_xor(l, 32, 64);
        float inv = 1.f / l;
        int qs0 = qw + s * 16;
        float part = 0.f;
#pragma unroll
        for (int mt = 0; mt < 4; ++mt) {
            float o0 = acc_o[s][mt][0] * inv;
            float o1 = acc_o[s][mt][1] * inv;
            float o2 = acc_o[s][mt][2] * inv;
            float o3 = acc_o[s][mt][3] * inv;
            part += o0 * o0 + o1 * o1 + o2 * o2 + o3 * o3;
            uint2 w2;
            w2.x = bf16pair(o0, o1);
            w2.y = bf16pair(o2, o3);
            // O[q = l16][d = mt*16 + quad*4 + ri]
            *(uint2*)(pp + l16 * 72 + mt * 16 + quad * 4) = w2;
        }
        part += __shfl_xor(part, 16, 64);
        part += __shfl_xor(part, 32, 64);
        if (quad == 0) atomicAdd(&osq[(size_t)b * TT + qs0 + l16], part);
        // coalesced store: lane covers row r = lane>>2, d = (lane&3)*16 .. +15
        int r = lane >> 2, cg = lane & 3;
        uint4 o0 = *(const uint4*)(pp + r * 72 + cg * 16);
        uint4 o1 = *(const uint4*)(pp + r * 72 + cg * 16 + 8);
        __hip_bfloat16* orow = out + (size_t)(b * TT + qs0 + r) * CC + h * DD + cg * 16;
        *(uint4*)(orow) = o0;
        *(uint4*)(orow + 8) = o1;
    }
}

// ---------------------------------------------------------------- launcher
extern "C" void kernel_launch(void* const* d_in, const int* in_sizes, int n_in,
                              void* d_out, int out_size, void* d_ws, size_t ws_size,
                              hipStream_t stream) {
    const float* x      = (const float*)d_in[0];
    // d_in[1] = mask (causal tril) — implied analytically, unused
    const float* w_attn = (const float*)d_in[2];
    const float* b_attn = (const float*)d_in[3];
    const float* w_proj = (const float*)d_in[4];
    const float* b_proj = (const float*)d_in[5];
    float* out = (float*)d_out;

    char* ws = (char*)d_ws;
    float*          qkv  = (float*)(ws + 0);                  // 4096x3072 fp32
    __hip_bfloat16* xbf  = (__hip_bfloat16*)(ws + 50331648);  // 4096x1024 bf16
    __hip_bfloat16* aout = (__hip_bfloat16*)(ws + 58720256);  // 4096x1024 bf16
    __hip_bfloat16* watT = (__hip_bfloat16*)(ws + 67108864);  // 3072x1024 bf16
    __hip_bfloat16* wpT  = (__hip_bfloat16*)(ws + 73400320);  // 1024x1024 bf16
    float*          rope = (float*)(ws + 75497472);           // 2048x32x2 fp32
    float*          xsq  = (float*)(ws + 76021760);           // 4096
    float*          osq  = (float*)(ws + 76038144);           // 4096
    float*          wsqa = (float*)(ws + 76054528);           // 3072
    float*          wsqp = (float*)(ws + 76066816);           // 1024
    __hip_bfloat16* Qb   = (__hip_bfloat16*)(ws + 76070912);  // [b,h,t,d] 8MB
    __hip_bfloat16* Kb   = (__hip_bfloat16*)(ws + 84459520);  // [b,h,t,d] 8MB
    __hip_bfloat16* Vtb  = (__hip_bfloat16*)(ws + 92848128);  // [b,h,d,t] 8MB

    float scale1 = (float)(sqrt(3072.0) / log1p(3072.0));
    float scale2 = (float)(sqrt(1024.0) / log1p(1024.0));

    hipMemsetAsync(wsqa, 0, 3072 * 4, stream);
    hipMemsetAsync(wsqp, 0, 1024 * 4, stream);
    hipMemsetAsync(osq, 0, ROWS * 4, stream);

    rope_init<<<256, 256, 0, stream>>>(rope);
    rowsq_cast<<<ROWS, 256, 0, stream>>>(x, xsq, xbf);
    transpose_colsq<<<dim3(N1 / 64, CC / 64), 256, 0, stream>>>(w_attn, watT, wsqa, CC, N1);
    transpose_colsq<<<dim3(CC / 64, CC / 64), 256, 0, stream>>>(w_proj, wpT, wsqp, CC, CC);
    yat_gemm_big<128, 128><<<dim3(N1 / 128, ROWS / 128), 256, 0, stream>>>(
        xbf, watT, xsq, wsqa, b_attn, qkv, ROWS, N1, CC, scale1);
    prep_qkv<<<dim3(TT / 64, HH, BB), 256, 0, stream>>>(qkv, rope, Qb, Kb, Vtb);
    attn_mfma2<<<512, 256, 0, stream>>>(Qb, Kb, Vtb, aout, osq);
    yat_gemm_big<128, 64><<<dim3(CC / 64, ROWS / 128), 256, 0, stream>>>(
        aout, wpT, osq, wsqp, b_proj, out, ROWS, CC, CC, scale2);
}